// Round 7
// baseline (395.864 us; speedup 1.0000x reference)
//
#include <hip/hip_runtime.h>
#include <math.h>

// Problem constants (from reference)
#define TT 10
#define SS 10
#define RR 2000
#define KK 100
#define OO 500
#define PP (TT*SS*RR)          // 200000 particles
#define NT16 12500             // 16-row tiles
#define NT 7                   // 7 N-tiles of 16 cols -> 112 padded assemblages
#define BLOCKT 256             // 4 waves per block
#define NBLK 1536              // 6 blocks/CU target -> 24 waves/CU
#define EPSF 1e-6f

typedef float        f32x4  __attribute__((ext_vector_type(4)));
typedef unsigned int u32x4  __attribute__((ext_vector_type(4)));
typedef __bf16       bf16x8 __attribute__((ext_vector_type(8)));

union BFU { bf16x8 v; u32x4 q; };

// ---------------------------------------------------------------------------
// Prep: theta = softmax -> out[1..50001); log(theta+eps) bf16 -> Bf in exact
// MFMA B-fragment order: word[(ko*7+nt)*64 + g*16 + lo] =
// logtheta[nt*16+lo][ko*32+g*8 .. +8]. Pad rows 100..111 -> 0.
// Also: beta copy -> out[50001..); out[0] = 0; tile counter = 0.
// ---------------------------------------------------------------------------
__global__ __launch_bounds__(64) void mcspace_prep(
    const float* __restrict__ theta_params,
    const float* __restrict__ beta,
    float* __restrict__ out,
    u32x4* __restrict__ Bf,
    unsigned* __restrict__ cnt)
{
    __shared__ float row[512];
    const int b  = blockIdx.x;
    const int ln = threadIdx.x;
    if (b < 112) {
        const int nt = b >> 4, lo = b & 15;
        const int ko = ln >> 2, g = ln & 3;
        if (b < KK) {
            const float* tp = theta_params + b * OO;
            float x[8];
            #pragma unroll
            for (int j = 0; j < 8; ++j) {
                int o = ln + 64 * j;
                x[j] = (o < OO) ? tp[o] : -INFINITY;
            }
            float mx = x[0];
            #pragma unroll
            for (int j = 1; j < 8; ++j) mx = fmaxf(mx, x[j]);
            #pragma unroll
            for (int w = 1; w < 64; w <<= 1) mx = fmaxf(mx, __shfl_xor(mx, w));
            float e[8], sm = 0.f;
            #pragma unroll
            for (int j = 0; j < 8; ++j) { e[j] = __expf(x[j] - mx); sm += e[j]; }
            #pragma unroll
            for (int w = 1; w < 64; w <<= 1) sm += __shfl_xor(sm, w);
            const float inv = 1.f / sm;
            #pragma unroll
            for (int j = 0; j < 8; ++j) {
                int o = ln + 64 * j;
                float th = e[j] * inv;            // 0 for o >= 500
                if (o < OO) out[1 + b * OO + o] = th;
                row[o] = th;
            }
            __syncthreads();
            BFU w8;
            #pragma unroll
            for (int i = 0; i < 8; ++i)
                w8.v[i] = (__bf16)__logf(row[ko * 32 + g * 8 + i] + EPSF);
            Bf[(ko * 7 + nt) * 64 + g * 16 + lo] = w8.q;
        } else {
            Bf[(ko * 7 + nt) * 64 + g * 16 + lo] = (u32x4){0u, 0u, 0u, 0u};
        }
    } else {
        int idx = (b - 112) * 64 + ln;
        if (idx < KK * TT * SS) out[1 + KK * OO + idx] = beta[idx];
        if (b == 112 && ln == 0) { out[0] = 0.f; cnt[0] = 0u; }
    }
}

// ---------------------------------------------------------------------------
// Main: zero-LDS, max-occupancy. A: direct global gather -> bf16 regs
// (R1-verified k-loop). B: fragment-ordered bf16 from L2-resident Bf.
// Dynamic tile distribution. 24 waves/CU target.
// ---------------------------------------------------------------------------
__global__ __launch_bounds__(BLOCKT, 6) void mcspace_main(
    const float* __restrict__ counts,
    const float* __restrict__ beta,
    const u32x4* __restrict__ Bf,
    unsigned* __restrict__ cnt,
    float* __restrict__ out)
{
    __shared__ float red[4];

    const int tid = threadIdx.x;
    const int wv  = tid >> 6;
    const int ln  = tid & 63;
    const int lo  = ln & 15;
    const int g   = ln >> 4;
    const int kb  = g * 8;

    const u32x4* bfl = Bf + ln;          // lane-fixed B base

    float wacc = 0.f;

    for (;;) {
        unsigned t = 0;
        if (ln == 0) t = atomicAdd(cnt, 1u);
        t = (unsigned)__shfl((int)t, 0);
        if (t >= NT16) break;

        const int ts = (int)t / 125;     // 125 tiles per (t,s)
        const float* rp = counts + (long)(t * 16 + lo) * OO;

        f32x4 acc[NT];
        #pragma unroll
        for (int nt = 0; nt < NT; ++nt) acc[nt] = (f32x4){0.f, 0.f, 0.f, 0.f};

        // prefetch k-step 0
        f32x4 a0 = *(const f32x4*)(rp + kb);
        f32x4 a1 = *(const f32x4*)(rp + kb + 4);

        // 15 full K-steps of 32 (k = 0..479), software-pipelined A loads
        for (int ko = 0; ko < 15; ++ko) {
            BFU a;
            #pragma unroll
            for (int j = 0; j < 4; ++j) {
                a.v[j]     = (__bf16)a0[j];
                a.v[4 + j] = (__bf16)a1[j];
            }
            // prefetch next k-step's A while this step computes
            if (ko < 14) {
                a0 = *(const f32x4*)(rp + (ko + 1) * 32 + kb);
                a1 = *(const f32x4*)(rp + (ko + 1) * 32 + kb + 4);
            }
            const u32x4* bp = bfl + (ko * NT) * 64;
            #pragma unroll
            for (int nt = 0; nt < NT; ++nt) {
                BFU bv; bv.q = bp[nt * 64];
                acc[nt] = __builtin_amdgcn_mfma_f32_16x16x32_bf16(a.v, bv.v, acc[nt], 0, 0, 0);
            }
        }
        // remainder K-step: k = 480..511, only k < 500 valid (masked loads)
        {
            BFU a;
            #pragma unroll
            for (int j = 0; j < 8; ++j) {
                int k = 480 + kb + j;
                a.v[j] = (__bf16)((k < OO) ? rp[k] : 0.f);
            }
            const u32x4* bp = bfl + (15 * NT) * 64;
            #pragma unroll
            for (int nt = 0; nt < NT; ++nt) {
                BFU bv; bv.q = bp[nt * 64];
                acc[nt] = __builtin_amdgcn_mfma_f32_16x16x32_bf16(a.v, bv.v, acc[nt], 0, 0, 0);
            }
        }

        // ---- beta-weighted logsumexp (in-register, R1-verified layout) ----
        float bet[NT];
        #pragma unroll
        for (int nt = 0; nt < NT; ++nt) {
            int j = nt * 16 + lo;
            bet[nt] = (j < KK) ? beta[j * (TT * SS) + ts] : 0.f;
        }
        float mrow[4] = {-INFINITY, -INFINITY, -INFINITY, -INFINITY};
        #pragma unroll
        for (int nt = 0; nt < NT; ++nt) {
            const bool valid = (nt * 16 + lo) < KK;
            #pragma unroll
            for (int r = 0; r < 4; ++r)
                mrow[r] = fmaxf(mrow[r], valid ? acc[nt][r] : -INFINITY);
        }
        #pragma unroll
        for (int w = 1; w < 16; w <<= 1) {
            #pragma unroll
            for (int r = 0; r < 4; ++r)
                mrow[r] = fmaxf(mrow[r], __shfl_xor(mrow[r], w));
        }
        float srow[4] = {0.f, 0.f, 0.f, 0.f};
        #pragma unroll
        for (int nt = 0; nt < NT; ++nt) {
            const bool valid = (nt * 16 + lo) < KK;
            #pragma unroll
            for (int r = 0; r < 4; ++r)
                srow[r] += bet[nt] * __expf(valid ? (acc[nt][r] - mrow[r]) : -INFINITY);
        }
        #pragma unroll
        for (int w = 1; w < 16; w <<= 1) {
            #pragma unroll
            for (int r = 0; r < 4; ++r)
                srow[r] += __shfl_xor(srow[r], w);
        }
        if (lo == 0) {
            #pragma unroll
            for (int r = 0; r < 4; ++r)
                wacc += mrow[r] + __logf(srow[r] + EPSF);
        }
    }

    // ---- deterministic block reduction, one atomic per block ----
    #pragma unroll
    for (int w = 1; w < 64; w <<= 1) wacc += __shfl_xor(wacc, w);
    if (ln == 0) red[wv] = wacc;
    __syncthreads();
    if (tid == 0) {
        float s = red[0] + red[1] + red[2] + red[3];
        atomicAdd(out, -s);   // elbo_loss = -loglik
    }
}

extern "C" void kernel_launch(void* const* d_in, const int* in_sizes, int n_in,
                              void* d_out, int out_size, void* d_ws, size_t ws_size,
                              hipStream_t stream)
{
    (void)in_sizes; (void)n_in; (void)ws_size; (void)out_size;
    const float* counts       = (const float*)d_in[0];
    const float* theta_params = (const float*)d_in[1];
    const float* beta         = (const float*)d_in[2];
    float* out    = (float*)d_out;
    unsigned* cnt = (unsigned*)d_ws;                       // tile counter
    u32x4* Bf     = (u32x4*)((char*)d_ws + 1024);          // 112 KB frag-ordered B

    // prep: 112 theta/Bf blocks + 157 beta-copy blocks
    mcspace_prep<<<dim3(112 + (KK * TT * SS + 63) / 64), dim3(64), 0, stream>>>(
        theta_params, beta, out, Bf, cnt);
    // main: 1536 blocks x 4 waves, zero-LDS, dynamic tiles
    mcspace_main<<<dim3(NBLK), dim3(BLOCKT), 0, stream>>>(
        counts, beta, Bf, cnt, out);
}